// Round 1
// baseline (299.803 us; speedup 1.0000x reference)
//
#include <hip/hip_runtime.h>

#define GRID 2048
#define BLK  256
#define NWAVES (BLK / 64)

// Grid-stride partial-sum kernel: each block writes 3 partial sums into ws.
// ws layout: ws[0..GRID) = near partials, ws[GRID..2*GRID) = midnear,
//            ws[2*GRID..3*GRID) = far.
__global__ __launch_bounds__(BLK) void pacmap_partial_kernel(
    const float4* __restrict__ nb, int n_n,
    const float4* __restrict__ mn, int n_m,
    const float4* __restrict__ fr, int n_f,
    float* __restrict__ ws) {

    float s_n = 0.0f, s_m = 0.0f, s_f = 0.0f;
    const int tid    = blockIdx.x * BLK + threadIdx.x;
    const int stride = GRID * BLK;

    // neighbor pairs: d/(10+d)
    for (int i = tid; i < n_n; i += stride) {
        float4 p = nb[i];
        float dx = p.x - p.z;
        float dy = p.y - p.w;
        float d  = fmaf(dx, dx, fmaf(dy, dy, 1.0f));
        s_n += d / (10.0f + d);
    }
    // midnear pairs: d/(10000+d)
    for (int i = tid; i < n_m; i += stride) {
        float4 p = mn[i];
        float dx = p.x - p.z;
        float dy = p.y - p.w;
        float d  = fmaf(dx, dx, fmaf(dy, dy, 1.0f));
        s_m += d / (10000.0f + d);
    }
    // far pairs: 1/(1+d)
    for (int i = tid; i < n_f; i += stride) {
        float4 p = fr[i];
        float dx = p.x - p.z;
        float dy = p.y - p.w;
        float d  = fmaf(dx, dx, fmaf(dy, dy, 1.0f));
        s_f += 1.0f / (1.0f + d);
    }

    // wave-64 shuffle reduction of all three accumulators
    #pragma unroll
    for (int off = 32; off > 0; off >>= 1) {
        s_n += __shfl_down(s_n, off, 64);
        s_m += __shfl_down(s_m, off, 64);
        s_f += __shfl_down(s_f, off, 64);
    }

    __shared__ float sm[3][NWAVES];
    const int lane = threadIdx.x & 63;
    const int wid  = threadIdx.x >> 6;
    if (lane == 0) {
        sm[0][wid] = s_n;
        sm[1][wid] = s_m;
        sm[2][wid] = s_f;
    }
    __syncthreads();
    if (threadIdx.x == 0) {
        float a = 0.0f, b = 0.0f, c = 0.0f;
        #pragma unroll
        for (int i = 0; i < NWAVES; ++i) {
            a += sm[0][i];
            b += sm[1][i];
            c += sm[2][i];
        }
        ws[blockIdx.x]            = a;
        ws[GRID + blockIdx.x]     = b;
        ws[2 * GRID + blockIdx.x] = c;
    }
}

// Single-block finalize: reduce GRID partials per loss, apply phase weights.
__global__ __launch_bounds__(BLK) void pacmap_finalize_kernel(
    const float* __restrict__ ws,
    const int* __restrict__ iter_p,
    float* __restrict__ out) {

    float s_n = 0.0f, s_m = 0.0f, s_f = 0.0f;
    for (int i = threadIdx.x; i < GRID; i += BLK) {
        s_n += ws[i];
        s_m += ws[GRID + i];
        s_f += ws[2 * GRID + i];
    }

    #pragma unroll
    for (int off = 32; off > 0; off >>= 1) {
        s_n += __shfl_down(s_n, off, 64);
        s_m += __shfl_down(s_m, off, 64);
        s_f += __shfl_down(s_f, off, 64);
    }

    __shared__ float sm[3][NWAVES];
    const int lane = threadIdx.x & 63;
    const int wid  = threadIdx.x >> 6;
    if (lane == 0) {
        sm[0][wid] = s_n;
        sm[1][wid] = s_m;
        sm[2][wid] = s_f;
    }
    __syncthreads();
    if (threadIdx.x == 0) {
        float a = 0.0f, b = 0.0f, c = 0.0f;
        #pragma unroll
        for (int i = 0; i < NWAVES; ++i) {
            a += sm[0][i];
            b += sm[1][i];
            c += sm[2][i];
        }

        const int it = *iter_p;
        float w_n, w_m, w_f;
        if (it < 101) {
            // phase 1: frac = (0-1)/(101-1) = -0.01 (constant within phase)
            const float frac = (0.0f - 1.0f) / (101.0f - 1.0f);
            w_n = 2.0f;
            w_m = 1000.0f * (1.0f - frac) + 3.0f * frac;
            w_f = 1.0f;
        } else if (it < 201) {
            w_n = 3.0f; w_m = 3.0f; w_f = 1.0f;
        } else {
            w_n = 1.0f; w_m = 0.0f; w_f = 1.0f;
        }
        out[0] = a * w_n + b * w_m + c * w_f;
    }
}

extern "C" void kernel_launch(void* const* d_in, const int* in_sizes, int n_in,
                              void* d_out, int out_size, void* d_ws, size_t ws_size,
                              hipStream_t stream) {
    const float4* nb = (const float4*)d_in[0];
    const float4* mn = (const float4*)d_in[1];
    const float4* fr = (const float4*)d_in[2];
    const int* iter_p = (const int*)d_in[3];

    const int n_n = in_sizes[0] / 4;  // pairs (each pair = 4 floats = 1 float4)
    const int n_m = in_sizes[1] / 4;
    const int n_f = in_sizes[2] / 4;

    float* ws  = (float*)d_ws;
    float* out = (float*)d_out;

    pacmap_partial_kernel<<<GRID, BLK, 0, stream>>>(nb, n_n, mn, n_m, fr, n_f, ws);
    pacmap_finalize_kernel<<<1, BLK, 0, stream>>>(ws, iter_p, out);
}